// Round 5
// baseline (96.465 us; speedup 1.0000x reference)
//
#include <hip/hip_runtime.h>

// Single-layer LSTM, input=1, hidden=1, zero init. One thread per row, serial over T.
// Chain-latency bound: per step the serial dependency is two sigmoid round-trips.
// This version:
//  - ONE rcp for the whole c-update (i,f,g merged):
//      c' = sf*c + si*g  ==  [cs*D + n2L*(1-Eg)*(1+Ef)] / [(1+Ei)(1+Eg)(1+Ef)]
//    with E* = 2^(u*), u* = -L*z* (sigmoid gates) / -2L*zg (tanh gate), cs = n2L*c.
//  - state kept as rc = rcp(1+Ec) so next-step gate preact is u = fma(rc, p2, am),
//    p2 = 2*c_h*so, am = a - c_h*so (both off-chain; tc=2rc-1 folded away).
//  - depth-8 register prefetch ring, chunked unroll-8, peeled last chunk (no clamps).

#define LOG2E 1.44269504088896340736f

__global__ __launch_bounds__(64) void lstm_h1_kernel(
    const float* __restrict__ x,
    const float* __restrict__ w_ih,
    const float* __restrict__ w_hh,
    const float* __restrict__ b_ih,
    const float* __restrict__ b_hh,
    float* __restrict__ out,
    int B, int T)
{
    int row = blockIdx.x * blockDim.x + threadIdx.x;
    if (row >= B) return;

    // Gate order: i, f, g, o. Combined bias.
    const float b0 = b_ih[0] + b_hh[0];
    const float b1 = b_ih[1] + b_hh[1];
    const float b2 = b_ih[2] + b_hh[2];
    const float b3 = b_ih[3] + b_hh[3];
    const float wi0 = w_ih[0], wi1 = w_ih[1], wi2 = w_ih[2], wi3 = w_ih[3];
    const float wh0 = w_hh[0], wh1 = w_hh[1], wh2 = w_hh[2], wh3 = w_hh[3];

    // Scaled coefficients: sigmoid gates by -L, tanh gate by -2L.
    const float ciw = -LOG2E * wi0,        cib = -LOG2E * b0,        cih = -LOG2E * wh0;
    const float cfw = -LOG2E * wi1,        cfb = -LOG2E * b1,        cfh = -LOG2E * wh1;
    const float cgw = -2.0f * LOG2E * wi2, cgb = -2.0f * LOG2E * b2, cgh = -2.0f * LOG2E * wh2;
    const float cow = -LOG2E * wi3,        cob = -LOG2E * b3,        coh = -LOG2E * wh3;
    const float n2L = -2.0f * LOG2E;       // cs = n2L * c

    // rc-state helper constants: p2_g = (2*c_gh)*so, am_g = a_g - c_gh*so.
    const float c2ih = 2.0f * cih, c2fh = 2.0f * cfh, c2gh = 2.0f * cgh, c2oh = 2.0f * coh;

    // State: rc = rcp(1+2^cs) (rc0=0.5 <=> tanh(c0)=0), cs = n2L*c, so_prev (0 => u=a).
    float rc = 0.5f, cs = 0.0f, so = 0.0f;

    const float4* __restrict__ xr = reinterpret_cast<const float4*>(x + (size_t)row * T);
    float4* __restrict__ yr = reinterpret_cast<float4*>(out + (size_t)row * T);

    const int nT4 = T >> 2;  // 256 float4-groups; chunks of 8 (32 steps)

#define LSTM_STEP(xx, hout)                                                   \
    {                                                                         \
        const float _x = (xx);                                                \
        /* x-dependent pre-activations */                                     \
        float ai = fmaf(_x, ciw, cib);                                        \
        float af = fmaf(_x, cfw, cfb);                                        \
        float ag = fmaf(_x, cgw, cgb);                                        \
        float ao = fmaf(_x, cow, cob);                                        \
        /* prev-step h folded: u = fma(rc, p2, am), using so from PREV step */\
        float p2i = c2ih * so, p2f = c2fh * so, p2g = c2gh * so, p2o = c2oh * so; \
        float ami = fmaf(cih, -so, ai);                                       \
        float amf = fmaf(cfh, -so, af);                                       \
        float amg = fmaf(cgh, -so, ag);                                       \
        float amo = fmaf(coh, -so, ao);                                       \
        float ui = fmaf(rc, p2i, ami);                                        \
        float uf = fmaf(rc, p2f, amf);                                        \
        float ug = fmaf(rc, p2g, amg);                                        \
        float uo = fmaf(rc, p2o, amo);                                        \
        float Ei = __builtin_amdgcn_exp2f(ui);                                \
        float Ef = __builtin_amdgcn_exp2f(uf);                                \
        float Eg = __builtin_amdgcn_exp2f(ug);                                \
        float Eo = __builtin_amdgcn_exp2f(uo);                                \
        float di = 1.0f + Ei;                                                 \
        float df = 1.0f + Ef;                                                 \
        float dg = 1.0f + Eg;                                                 \
        float dd = 1.0f + Eo;                                                 \
        float D  = di * dg;                                                   \
        float D2 = D * df;                                                    \
        float Q2 = __builtin_amdgcn_rcpf(D2);                                 \
        float t  = 1.0f - Eg;                                                 \
        float nt = n2L * t;                                                   \
        float csD = cs * D;                                                   \
        float num = fmaf(nt, df, csD);                                        \
        cs = num * Q2;                                                        \
        float Ec = __builtin_amdgcn_exp2f(cs);                                \
        float dc = 1.0f + Ec;                                                 \
        rc = __builtin_amdgcn_rcpf(dc);                                       \
        so = __builtin_amdgcn_rcpf(dd);                                       \
        float tc = fmaf(2.0f, rc, -1.0f);                                     \
        (hout) = so * tc;                                                     \
    }

#define LSTM_STEP4(xv, base_k)                                                \
    {                                                                         \
        float4 _hv;                                                           \
        LSTM_STEP((xv).x, _hv.x);                                             \
        LSTM_STEP((xv).y, _hv.y);                                             \
        LSTM_STEP((xv).z, _hv.z);                                             \
        LSTM_STEP((xv).w, _hv.w);                                             \
        yr[(base_k)] = _hv;                                                   \
    }

    // Depth-8 prefetch ring.
    float4 buf0 = xr[0], buf1 = xr[1], buf2 = xr[2], buf3 = xr[3];
    float4 buf4 = xr[4], buf5 = xr[5], buf6 = xr[6], buf7 = xr[7];

    int base = 0;
    for (; base + 8 < nT4; base += 8) {
        const float4* nx = xr + base + 8;
        float4 xv;
        xv = buf0; buf0 = nx[0]; LSTM_STEP4(xv, base + 0);
        xv = buf1; buf1 = nx[1]; LSTM_STEP4(xv, base + 1);
        xv = buf2; buf2 = nx[2]; LSTM_STEP4(xv, base + 2);
        xv = buf3; buf3 = nx[3]; LSTM_STEP4(xv, base + 3);
        xv = buf4; buf4 = nx[4]; LSTM_STEP4(xv, base + 4);
        xv = buf5; buf5 = nx[5]; LSTM_STEP4(xv, base + 5);
        xv = buf6; buf6 = nx[6]; LSTM_STEP4(xv, base + 6);
        xv = buf7; buf7 = nx[7]; LSTM_STEP4(xv, base + 7);
    }
    // Peeled last chunk (no prefetch loads, no clamps).
    LSTM_STEP4(buf0, base + 0);
    LSTM_STEP4(buf1, base + 1);
    LSTM_STEP4(buf2, base + 2);
    LSTM_STEP4(buf3, base + 3);
    LSTM_STEP4(buf4, base + 4);
    LSTM_STEP4(buf5, base + 5);
    LSTM_STEP4(buf6, base + 6);
    LSTM_STEP4(buf7, base + 7);

#undef LSTM_STEP4
#undef LSTM_STEP
}

extern "C" void kernel_launch(void* const* d_in, const int* in_sizes, int n_in,
                              void* d_out, int out_size, void* d_ws, size_t ws_size,
                              hipStream_t stream) {
    const float* x    = (const float*)d_in[0];
    const float* w_ih = (const float*)d_in[1];
    const float* w_hh = (const float*)d_in[2];
    const float* b_ih = (const float*)d_in[3];
    const float* b_hh = (const float*)d_in[4];
    float* out = (float*)d_out;

    const int T = 1024;
    const int B = in_sizes[0] / T;  // x has B*T*1 elements

    const int block = 64;
    const int grid = (B + block - 1) / block;
    lstm_h1_kernel<<<grid, block, 0, stream>>>(x, w_ih, w_hh, b_ih, b_hh, out, B, T);
}